// Round 8
// baseline (127.990 us; speedup 1.0000x reference)
//
#include <hip/hip_runtime.h>
#include <hip/hip_bf16.h>

// One-hot: label (H*W int32) -> out (N, H, W) float32.
// Ideal traffic = 64 MiB read + 512 MiB write (~96 us at copy-class 6.5 TB/s).
//
// Journal:
//  R1 (8 plane-streams/thread, read-once):    130 us (8 concurrent 64MiB-apart write windows = 4.6 TB/s)
//  R3 (nontemporal stores):                   250 us (nt bypasses L2 write-combine -> partial-line RMW; never)
//  R4 (plane per blockIdx.y, 1 write window): 146 us (writes fast; 64MiB int32 re-fetch thrashed L3)
//  R5 (wave-per-plane, staggered):            153 us (still 8 concurrent aliased windows)
//  R6 (pack u8 + 16px/thread expand):         185 us (per-THREAD-contiguous stores broke coalescing.
//                                               LESSON: per-instruction lane-contiguity is mandatory)
//  R7 (pack u8 + plane-serial, 4px/thread):   118 us (works; but 16MiB packed array re-read x8 through
//                                               an L3 being turned over 2x by the write stream)
//
// R8: pack to per-plane BITMAPS (1 bit/px, 2 MiB/plane). Pass n reads only
// its own bitmap, each byte exactly once -> zero reliance on L3 retention.
// k2 blocks do 8 wave-strided float4 stores (lane-contiguous per instruction),
// 16384 blocks total (8x fewer dispatches, 8x more ILP per thread).

typedef unsigned int u32;

// k1: label(int32) -> 8 bitplanes. Thread t owns 32 px -> one u32 word/plane.
// Build 3 value-bitplanes (b0,b1,b2 = bits of the label value), then each
// plane mask is an AND of (b_k or ~b_k) — ~9 VALU/px instead of 24.
__global__ void __launch_bounds__(256) pack_bits_kernel(
    const int* __restrict__ label, u32* __restrict__ bits, int total) {
    int words = total >> 5;
    int t = blockIdx.x * 256 + threadIdx.x;
    if (t >= words) return;
    const int4* lp = reinterpret_cast<const int4*>(label) + (long long)t * 8;
    u32 b0 = 0, b1 = 0, b2 = 0;
#pragma unroll
    for (int q = 0; q < 8; ++q) {
        int4 a = lp[q];
        int j = q * 4;
        b0 |= (u32)(a.x & 1) << j;      b1 |= (u32)((a.x >> 1) & 1) << j;      b2 |= (u32)((a.x >> 2) & 1) << j;
        b0 |= (u32)(a.y & 1) << (j+1);  b1 |= (u32)((a.y >> 1) & 1) << (j+1);  b2 |= (u32)((a.y >> 2) & 1) << (j+1);
        b0 |= (u32)(a.z & 1) << (j+2);  b1 |= (u32)((a.z >> 1) & 1) << (j+2);  b2 |= (u32)((a.z >> 2) & 1) << (j+2);
        b0 |= (u32)(a.w & 1) << (j+3);  b1 |= (u32)((a.w >> 1) & 1) << (j+3);  b2 |= (u32)((a.w >> 2) & 1) << (j+3);
    }
    u32 n0 = ~b0, n1 = ~b1, n2 = ~b2;
    bits[0 * words + t] = n2 & n1 & n0;
    bits[1 * words + t] = n2 & n1 & b0;
    bits[2 * words + t] = n2 & b1 & n0;
    bits[3 * words + t] = n2 & b1 & b0;
    bits[4 * words + t] = b2 & n1 & n0;
    bits[5 * words + t] = b2 & n1 & b0;
    bits[6 * words + t] = b2 & b1 & n0;
    bits[7 * words + t] = b2 & b1 & b0;
}

// k2: one plane per blockIdx.y; block expands 8192 px (256 bitmap words).
// Iteration it: lane tid stores float4 at px = it*1024 + tid*4 (lane-contiguous
// 1 KiB/wave/instr); its 4 bits live in word it*32 + (tid>>3), nibble (tid&7)*4
// (8-lane broadcast load, 32B/wave/instr).
__global__ void __launch_bounds__(256) expand_bits_kernel(
    const u32* __restrict__ bits, float* __restrict__ out, int total) {
    const int n = blockIdx.y;
    const int tid = threadIdx.x;
    const int words = total >> 5;
    const u32* wp = bits + (long long)n * words + (long long)blockIdx.x * 256;
    float* op = out + (long long)n * total + (long long)blockIdx.x * 8192;
    const int sh = (tid & 7) * 4;
    const int wofs = tid >> 3;
#pragma unroll
    for (int it = 0; it < 8; ++it) {
        u32 w = wp[it * 32 + wofs];
        u32 nib = w >> sh;
        float4 v;
        v.x = (nib & 1u) ? 1.0f : 0.0f;
        v.y = (nib & 2u) ? 1.0f : 0.0f;
        v.z = (nib & 4u) ? 1.0f : 0.0f;
        v.w = (nib & 8u) ? 1.0f : 0.0f;
        *reinterpret_cast<float4*>(op + it * 1024 + tid * 4) = v;
    }
}

// Fallback (R1 structure) if N != 8 or ws too small.
__global__ void __launch_bounds__(256) get_one_hot_generic_kernel(
    const int* __restrict__ label, float* __restrict__ out,
    int total, int N) {
    long long i = ((long long)blockIdx.x * blockDim.x + threadIdx.x) * 4;
    if (i >= total) return;
    int4 lab = *reinterpret_cast<const int4*>(label + i);
    for (int n = 0; n < N; ++n) {
        float4 v;
        v.x = (lab.x == n) ? 1.0f : 0.0f;
        v.y = (lab.y == n) ? 1.0f : 0.0f;
        v.z = (lab.z == n) ? 1.0f : 0.0f;
        v.w = (lab.w == n) ? 1.0f : 0.0f;
        *reinterpret_cast<float4*>(out + (long long)n * total + i) = v;
    }
}

extern "C" void kernel_launch(void* const* d_in, const int* in_sizes, int n_in,
                              void* d_out, int out_size, void* d_ws, size_t ws_size,
                              hipStream_t stream) {
    const int* label = (const int*)d_in[0];
    float* out = (float*)d_out;

    int total = in_sizes[0];          // H*W = 16,777,216
    int N = out_size / total;         // 8

    // bitplane bytes = (total/32)*4*8 = total bytes
    bool fast = (N == 8) && (total % 8192 == 0) && (ws_size >= (size_t)total);
    if (fast) {
        int words = total >> 5;
        pack_bits_kernel<<<words / 256, 256, 0, stream>>>(label, (u32*)d_ws, total);
        dim3 grid(total / 8192, N);   // 2048 x 8; x fastest -> plane-serial passes
        expand_bits_kernel<<<grid, 256, 0, stream>>>((const u32*)d_ws, out, total);
    } else {
        int grid = (total / 4 + 255) / 256;
        get_one_hot_generic_kernel<<<grid, 256, 0, stream>>>(label, out, total, N);
    }
}